// Round 6
// baseline (168.746 us; speedup 1.0000x reference)
//
#include <hip/hip_runtime.h>

#define LSEQ 384
#define NROWS 1536      // B*L
#define FDIM 640
#define HDIM 128
#define PART 196608     // 1536*128

// ws layout (float indices)
#define WS_H1P 0                 // 4 x PART (H1 split-K partials)
#define WS_FIP (4*PART)          // 4 x PART
#define WS_FJP (8*PART)          // 4 x PART
#define WS_FI  (12*PART)         // final fi
#define WS_FJ  (13*PART)         // final fj
#define WS_QC  (14*PART)
#define WS_FLAG (WS_QC + NROWS)   // int[1536]
#define WS_EPART (WS_FLAG + NROWS) // float[384]: 4 batches x 96 energy slots
#define WS_DONE  (WS_EPART + 384)  // uint[1]

// out layout (float indices)
#define OUT_PC    0
#define OUT_TC    4608
#define OUT_NET   9216
#define OUT_POT   10752
#define OUT_MASK  12288
#define OUT_EN    602112

// =========== Kernel 1: uniform split-K=4 GEMM, double-buffered ===========
// grid (48, 6, 4). BM=32, BN=64, BK=32, 256 threads, acc 2x4.
__global__ __launch_bounds__(256) void k_gemm(const float* __restrict__ X,
                                              const float* __restrict__ W1,
                                              const float* __restrict__ sW1,
                                              float* __restrict__ ws) {
    __shared__ float As[2 * 32 * 34];
    __shared__ float Bs[2 * 32 * 64];
    const int t = threadIdx.x;
    if (blockIdx.x == 0 && blockIdx.y == 0 && blockIdx.z == 0) {
        for (int idx = t; idx < 385; idx += 256)   // energy slots + done counter
            ws[WS_EPART + idx] = 0.0f;
    }

    const int m0 = blockIdx.x * 32;
    const int gy = blockIdx.y, kz = blockIdx.z;
    const int mat = gy >> 1, half = gy & 1, n0 = half * 64;
    const float* W = (mat == 0) ? W1 : (mat == 1 ? sW1 : sW1 + 640 * 128);
    float* O = ws + (mat == 0 ? WS_H1P : (mat == 1 ? WS_FIP : WS_FJP)) + kz * PART;

    const int a_r = t >> 3, a_c = (t & 7) * 4;
    const int b_r = t >> 4, b_c = (t & 15) * 4;
    const int tx = (t & 15) * 4, ty = (t >> 4) * 2;
    const int k0 = kz * 160;

    float acc[2][4] = {};

    float4 av  = *(const float4*)&X[(m0 + a_r) * FDIM + k0 + a_c];
    float4 bv0 = *(const float4*)&W[(k0 + b_r) * HDIM + n0 + b_c];
    float4 bv1 = *(const float4*)&W[(k0 + b_r + 16) * HDIM + n0 + b_c];
    As[(a_c + 0) * 34 + a_r] = av.x;
    As[(a_c + 1) * 34 + a_r] = av.y;
    As[(a_c + 2) * 34 + a_r] = av.z;
    As[(a_c + 3) * 34 + a_r] = av.w;
    *(float4*)&Bs[b_r * 64 + b_c]        = bv0;
    *(float4*)&Bs[(b_r + 16) * 64 + b_c] = bv1;
    __syncthreads();

    for (int it = 0; it < 5; it++) {
        const int buf = it & 1;
        if (it < 4) {
            const int kk = k0 + (it + 1) * 32;
            av  = *(const float4*)&X[(m0 + a_r) * FDIM + kk + a_c];
            bv0 = *(const float4*)&W[(kk + b_r) * HDIM + n0 + b_c];
            bv1 = *(const float4*)&W[(kk + b_r + 16) * HDIM + n0 + b_c];
        }
        const float* Ab = As + buf * 1088;
        const float* Bb = Bs + buf * 2048;
#pragma unroll
        for (int k = 0; k < 32; k++) {
            float2 a = *(const float2*)&Ab[k * 34 + ty];
            float4 b = *(const float4*)&Bb[k * 64 + tx];
            acc[0][0] = fmaf(a.x, b.x, acc[0][0]);
            acc[0][1] = fmaf(a.x, b.y, acc[0][1]);
            acc[0][2] = fmaf(a.x, b.z, acc[0][2]);
            acc[0][3] = fmaf(a.x, b.w, acc[0][3]);
            acc[1][0] = fmaf(a.y, b.x, acc[1][0]);
            acc[1][1] = fmaf(a.y, b.y, acc[1][1]);
            acc[1][2] = fmaf(a.y, b.z, acc[1][2]);
            acc[1][3] = fmaf(a.y, b.w, acc[1][3]);
        }
        if (it < 4) {
            float* Aw = As + (buf ^ 1) * 1088;
            float* Bw = Bs + (buf ^ 1) * 2048;
            Aw[(a_c + 0) * 34 + a_r] = av.x;
            Aw[(a_c + 1) * 34 + a_r] = av.y;
            Aw[(a_c + 2) * 34 + a_r] = av.z;
            Aw[(a_c + 3) * 34 + a_r] = av.w;
            *(float4*)&Bw[b_r * 64 + b_c]        = bv0;
            *(float4*)&Bw[(b_r + 16) * 64 + b_c] = bv1;
            __syncthreads();
        }
    }
#pragma unroll
    for (int r = 0; r < 2; r++) {
        float4 v = make_float4(acc[r][0], acc[r][1], acc[r][2], acc[r][3]);
        *(float4*)&O[(m0 + ty + r) * HDIM + n0 + tx] = v;
    }
}

// =========== Kernel 2: partial reduce + row epilogue ===========
__global__ __launch_bounds__(256) void k_row(float* __restrict__ ws,
                                             const float* __restrict__ b1,
                                             const float* __restrict__ gam,
                                             const float* __restrict__ bet,
                                             const float* __restrict__ rmean,
                                             const float* __restrict__ rvar,
                                             const float* __restrict__ W2,
                                             const float* __restrict__ b2,
                                             const float* __restrict__ W3,
                                             const float* __restrict__ b3,
                                             const int* __restrict__ seq,
                                             float* __restrict__ out) {
    const int t = threadIdx.x, w = t >> 6, lane = t & 63;
    const int row = blockIdx.x * 4 + w;
    const long base = (long)row * 128;
    const float* h1p = ws + WS_H1P;
    const float* fip = ws + WS_FIP;
    const float* fjp = ws + WS_FJP;

    {
        float fi0 = fip[base + lane] + fip[PART + base + lane]
                  + fip[2 * PART + base + lane] + fip[3 * PART + base + lane];
        float fi1 = fip[base + 64 + lane] + fip[PART + base + 64 + lane]
                  + fip[2 * PART + base + 64 + lane] + fip[3 * PART + base + 64 + lane];
        float fj0 = fjp[base + lane] + fjp[PART + base + lane]
                  + fjp[2 * PART + base + lane] + fjp[3 * PART + base + lane];
        float fj1 = fjp[base + 64 + lane] + fjp[PART + base + 64 + lane]
                  + fjp[2 * PART + base + 64 + lane] + fjp[3 * PART + base + 64 + lane];
        ws[WS_FI + base + lane]      = fi0;
        ws[WS_FI + base + 64 + lane] = fi1;
        ws[WS_FJ + base + lane]      = fj0;
        ws[WS_FJ + base + 64 + lane] = fj1;
    }

    float h0 = h1p[base + lane] + h1p[PART + base + lane]
             + h1p[2 * PART + base + lane] + h1p[3 * PART + base + lane];
    float h1 = h1p[base + 64 + lane] + h1p[PART + base + 64 + lane]
             + h1p[2 * PART + base + 64 + lane] + h1p[3 * PART + base + 64 + lane];
    h0 = fmaxf(h0 + b1[lane], 0.0f);
    h1 = fmaxf(h1 + b1[64 + lane], 0.0f);
    h0 = gam[lane]      * (h0 - rmean[lane])      / sqrtf(rvar[lane] + 1e-5f)      + bet[lane];
    h1 = gam[64 + lane] * (h1 - rmean[64 + lane]) / sqrtf(rvar[64 + lane] + 1e-5f) + bet[64 + lane];

    float acc = b2[lane];
#pragma unroll
    for (int cc = 0; cc < 64; cc++) {
        float wv0 = W2[cc * 64 + lane];
        float wv1 = W2[(cc + 64) * 64 + lane];
        float hv0 = __uint_as_float(__builtin_amdgcn_readlane(__float_as_uint(h0), cc));
        float hv1 = __uint_as_float(__builtin_amdgcn_readlane(__float_as_uint(h1), cc));
        acc = fmaf(hv0, wv0, acc);
        acc = fmaf(hv1, wv1, acc);
    }
    float h2 = fmaxf(acc, 0.0f);
    float x0 = h2 * W3[lane * 3 + 0];
    float x1 = h2 * W3[lane * 3 + 1];
    float x2 = h2 * W3[lane * 3 + 2];
#pragma unroll
    for (int o = 32; o > 0; o >>= 1) {
        x0 += __shfl_xor(x0, o, 64);
        x1 += __shfl_xor(x1, o, 64);
        x2 += __shfl_xor(x2, o, 64);
    }
    if (lane == 0) {
        float l0 = x0 + b3[0], l1 = x1 + b3[1], l2 = x2 + b3[2];
        float m = fmaxf(l0, fmaxf(l1, l2));
        float e0 = expf(l0 - m), e1 = expf(l1 - m), e2 = expf(l2 - m);
        float s = e0 + e1 + e2;
        float pc0 = e0 / s, pc1 = e1 / s, pc2 = e2 / s;
        out[OUT_PC + row * 3 + 0] = pc0;
        out[OUT_PC + row * 3 + 1] = pc1;
        out[OUT_PC + row * 3 + 2] = pc2;
        float net = pc0 - pc1;
        out[OUT_NET + row] = net;
        ws[WS_QC + row] = net;
        ((int*)(ws + WS_FLAG))[row] = (pc0 > pc2 ? 1 : 0) | (pc1 > pc2 ? 2 : 0);
        int sid = seq[row];
        float c0 = (sid == 6 || sid == 8 || sid == 14) ? 1.0f : 0.0f;
        float c1 = (sid == 2 || sid == 3) ? 1.0f : 0.0f;
        out[OUT_TC + row * 3 + 0] = c0;
        out[OUT_TC + row * 3 + 1] = c1;
        out[OUT_TC + row * 3 + 2] = (c0 == 0.0f && c1 == 0.0f) ? 1.0f : 0.0f;
    }
}

// =========== Kernel 3: conv (register recompute) + pair sweep + inline MLP ===========
__device__ __forceinline__ float mlp_eval(const float* __restrict__ fi, const float* __restrict__ fj,
                                          int gi, int gj, float D,
                                          float dv0, float dv1, float sb0, float sb1v,
                                          float b2v, float w3l, const float* __restrict__ sW2, int lane) {
    float h0 = fmaxf(fi[(long)gi * 128 + lane]      + fj[(long)gj * 128 + lane]      + D * dv0 + sb0,  0.0f);
    float h1 = fmaxf(fi[(long)gi * 128 + 64 + lane] + fj[(long)gj * 128 + 64 + lane] + D * dv1 + sb1v, 0.0f);
    float a0 = 0.0f, a1 = 0.0f;
#pragma unroll 8
    for (int cc = 0; cc < 64; cc++) {
        float hv0 = __uint_as_float(__builtin_amdgcn_readlane(__float_as_uint(h0), cc));
        float hv1 = __uint_as_float(__builtin_amdgcn_readlane(__float_as_uint(h1), cc));
        a0 = fmaf(hv0, sW2[cc * 64 + lane], a0);
        a1 = fmaf(hv1, sW2[(cc + 64) * 64 + lane], a1);
    }
    float x = fmaxf(a0 + a1 + b2v, 0.0f) * w3l;
#pragma unroll
    for (int o = 32; o > 0; o >>= 1) x += __shfl_xor(x, o, 64);
    return x;
}

__global__ __launch_bounds__(256, 6) void k2(const float* __restrict__ S,
                                             float* __restrict__ ws,
                                             const float* __restrict__ sW1,
                                             const float* __restrict__ sb1,
                                             const float* __restrict__ sW2,
                                             const float* __restrict__ sb2,
                                             const float* __restrict__ sW3,
                                             const float* __restrict__ sb3,
                                             const float* __restrict__ c1w, const float* __restrict__ c1b,
                                             const float* __restrict__ c2w, const float* __restrict__ c2b,
                                             const float* __restrict__ c3w, const float* __restrict__ c3b,
                                             float* __restrict__ out) {
    __shared__ char smem[8192];
    const int t = threadIdx.x;
    const int bi = blockIdx.x;

    if (bi < 4) {
        // conv via per-position register recompute; LDS = padded p0 only.
        float* p0h = (float*)smem;   // 392 floats: positions -4..387, zero-padded
        const int b = bi;
        for (int idx = t; idx < 392; idx += 256)
            p0h[idx] = (idx >= 4 && idx < 388) ? out[OUT_NET + b * LSEQ + (idx - 4)] : 0.0f;
        __syncthreads();
        for (int pos = t; pos < LSEQ; pos += 256) {
            float p2v[8][3];
#pragma unroll
            for (int o2 = 0; o2 < 8; o2++) {
                float cb = c2b[o2];
#pragma unroll
                for (int d1 = 0; d1 < 3; d1++) p2v[o2][d1] = cb;
            }
            for (int i = 0; i < 16; i++) {
                float p1v[5];
#pragma unroll
                for (int d2 = 0; d2 < 5; d2++) {
                    int q2 = pos - 2 + d2;
                    float a = c1b[i];
#pragma unroll
                    for (int k = 0; k < 5; k++)
                        a = fmaf(p0h[q2 + 2 + k], c1w[i * 5 + k], a);
                    p1v[d2] = (q2 >= 0 && q2 < LSEQ) ? fmaxf(a, 0.0f) : 0.0f;
                }
#pragma unroll
                for (int o2 = 0; o2 < 8; o2++) {
#pragma unroll
                    for (int d1 = 0; d1 < 3; d1++) {
#pragma unroll
                        for (int k = 0; k < 3; k++)
                            p2v[o2][d1] = fmaf(p1v[d1 + k], c2w[(o2 * 16 + i) * 3 + k], p2v[o2][d1]);
                    }
                }
            }
            float acc3 = c3b[0];
#pragma unroll
            for (int o2 = 0; o2 < 8; o2++) {
#pragma unroll
                for (int k = 0; k < 3; k++) {
                    int q1 = pos - 1 + k;
                    float pv = (q1 >= 0 && q1 < LSEQ) ? fmaxf(p2v[o2][k], 0.0f) : 0.0f;
                    acc3 = fmaf(pv, c3w[o2 * 3 + k], acc3);
                }
            }
            out[OUT_POT + b * LSEQ + pos] = acc3;
        }
        return;
    }

    float* sx = (float*)smem;                          // 384 f
    float* sy = sx + 384;
    float* sz = sy + 384;
    float* sq = sz + 384;
    unsigned int* clist = (unsigned int*)(sq + 384);   // 384 u32
    unsigned char* sf = (unsigned char*)(smem + 7680); // 384 B
    float* red = (float*)(smem + 8064);                // 4 f
    int* cntL = (int*)(smem + 8080);

    const float* qc = ws + WS_QC;
    const int* flags = (const int*)(ws + WS_FLAG);
    const float* fi = ws + WS_FI;
    const float* fj = ws + WS_FJ;

    const int row = bi - 4;
    const int b = row / LSEQ;
    const int i = row - b * LSEQ;

    for (int j = t; j < LSEQ; j += 256) {
        int g = b * LSEQ + j;
        sx[j] = S[g * 3 + 0];
        sy[j] = S[g * 3 + 1];
        sz[j] = S[g * 3 + 2];
        sq[j] = qc[g];
        sf[j] = (unsigned char)flags[g];
    }
    if (t == 0) *cntL = 0;
    __syncthreads();

    const float six = sx[i], siy = sy[i], siz = sz[i], qi = sq[i];
    const int fli = sf[i];
    const bool posi = (fli & 1) != 0, negi = (fli & 2) != 0;
    const int lane = t & 63, w = t >> 6;
    float esum = 0.0f;
    float* mrow = out + OUT_MASK + (long)row * LSEQ;

    for (int j = t; j < LSEQ; j += 256) {
        float dx = __fsub_rn(six, sx[j]);
        float dy = __fsub_rn(siy, sy[j]);
        float dz = __fsub_rn(siz, sz[j]);
        float d2 = __fadd_rn(__fadd_rn(__fmul_rn(dx, dx), __fmul_rn(dy, dy)), __fmul_rn(dz, dz));
        d2 = __fadd_rn(d2, 1e-12f);
        float D = __fsqrt_rn(d2);
        mrow[j] = 0.0f;
        if (j > i && D < 15.0f && D > 0.0f) {
            float num = __fmul_rn(__fmul_rn(332.0f, qi), sq[j]);
            float den = __fmul_rn(__fmul_rn(20.0f, D), D);
            esum += __fdiv_rn(num, den);
        }
        int flj = sf[j];
        bool near = (D < 4.0f);
        bool need1 = near && posi && ((flj & 2) != 0);
        bool need2 = near && negi && ((flj & 1) != 0);
        if (need1 || need2) {
            int p = atomicAdd(cntL, 1);
            clist[p] = (unsigned int)j | (need1 ? 512u : 0u) | (need2 ? 1024u : 0u);
        }
    }
#pragma unroll
    for (int o = 32; o > 0; o >>= 1) esum += __shfl_xor(esum, o, 64);
    if (lane == 0) red[w] = esum;
    __syncthreads();

    int nc = *cntL;
    float blockE = red[0] + red[1] + red[2] + red[3];

    if (nc > 0) {
        const float* dvec = sW1 + 1280 * 128;
        const float dv0 = dvec[lane], dv1 = dvec[lane + 64];
        const float sb0 = sb1[lane], sb1v = sb1[lane + 64];
        const float w3l = sW3[lane];
        const float b2v = sb2[lane];
        const float b3v = sb3[0];
        for (int c = w; c < nc; c += 4) {
            unsigned int e = clist[c];
            int j = (int)(e & 511u);
            bool need1 = (e & 512u) != 0, need2 = (e & 1024u) != 0;
            float dx = __fsub_rn(six, sx[j]);
            float dy = __fsub_rn(siy, sy[j]);
            float dz = __fsub_rn(siz, sz[j]);
            float d2 = __fadd_rn(__fadd_rn(__fmul_rn(dx, dx), __fmul_rn(dy, dy)), __fmul_rn(dz, dz));
            d2 = __fadd_rn(d2, 1e-12f);
            float D = __fsqrt_rn(d2);
            int gi = row, gj = b * LSEQ + j;
            bool hit = false;
            if (need1) {
                float x = mlp_eval(fi, fj, gi, gj, D, dv0, dv1, sb0, sb1v, b2v, w3l, sW2, lane);
                hit = (x + b3v) > 0.0f;
            }
            if (!hit && need2) {
                float x = mlp_eval(fi, fj, gj, gi, D, dv0, dv1, sb0, sb1v, b2v, w3l, sW2, lane);
                hit = (x + b3v) > 0.0f;
            }
            if (hit && lane == 0) mrow[j] = 1.0f;
        }
    }

    // energy: spread atomics (96 slots/batch) + done-counter, last block finalizes
    unsigned int old = 0xffffffffu;
    if (t == 0) {
        atomicAdd(&ws[WS_EPART + b * 96 + (i % 96)], blockE);
        __threadfence();
        old = atomicAdd((unsigned int*)&ws[WS_DONE], 1u);
    }
    if (t < 64) {
        old = __shfl(old, 0, 64);
        if (old == (unsigned int)(NROWS - 1)) {
#pragma unroll
            for (int bb = 0; bb < 4; bb++) {
                float s = ws[WS_EPART + bb * 96 + lane];
                if (lane < 32) s += ws[WS_EPART + bb * 96 + 64 + lane];
#pragma unroll
                for (int o = 32; o > 0; o >>= 1) s += __shfl_xor(s, o, 64);
                if (lane == 0) out[OUT_EN + bb] = s;
            }
        }
    }
}

extern "C" void kernel_launch(void* const* d_in, const int* in_sizes, int n_in,
                              void* d_out, int out_size, void* d_ws, size_t ws_size,
                              hipStream_t stream) {
    const float* X     = (const float*)d_in[0];
    const int*   seq   = (const int*)d_in[1];
    const float* S     = (const float*)d_in[2];
    const float* W1    = (const float*)d_in[3];
    const float* b1    = (const float*)d_in[4];
    const float* gam   = (const float*)d_in[5];
    const float* bet   = (const float*)d_in[6];
    const float* rmean = (const float*)d_in[7];
    const float* rvar  = (const float*)d_in[8];
    const float* W2    = (const float*)d_in[9];
    const float* b2    = (const float*)d_in[10];
    const float* W3    = (const float*)d_in[11];
    const float* b3    = (const float*)d_in[12];
    const float* sW1   = (const float*)d_in[13];
    const float* sb1   = (const float*)d_in[14];
    const float* sW2   = (const float*)d_in[15];
    const float* sb2   = (const float*)d_in[16];
    const float* sW3   = (const float*)d_in[17];
    const float* sb3   = (const float*)d_in[18];
    const float* c1w   = (const float*)d_in[19];
    const float* c1b   = (const float*)d_in[20];
    const float* c2w   = (const float*)d_in[21];
    const float* c2b   = (const float*)d_in[22];
    const float* c3w   = (const float*)d_in[23];
    const float* c3b   = (const float*)d_in[24];

    float* out = (float*)d_out;
    float* ws  = (float*)d_ws;

    hipLaunchKernelGGL(k_gemm, dim3(48, 6, 4), dim3(256), 0, stream, X, W1, sW1, ws);
    hipLaunchKernelGGL(k_row, dim3(384), dim3(256), 0, stream,
                       ws, b1, gam, bet, rmean, rvar, W2, b2, W3, b3, seq, out);
    hipLaunchKernelGGL(k2, dim3(1540), dim3(256), 0, stream,
                       S, ws, sW1, sb1, sW2, sb2, sW3, sb3,
                       c1w, c1b, c2w, c2b, c3w, c3b, out);
}

// Round 7
// 165.407 us; speedup vs baseline: 1.0202x; 1.0202x over previous
//
#include <hip/hip_runtime.h>

#define LSEQ 384
#define NROWS 1536      // B*L
#define FDIM 640
#define HDIM 128
#define PART 196608     // 1536*128

// ws layout (float indices)
#define WS_H1P 0                 // 4 x PART (H1 split-K partials)
#define WS_FIP (4*PART)          // 4 x PART
#define WS_FJP (8*PART)          // 4 x PART
#define WS_FI  (12*PART)         // final fi
#define WS_FJ  (13*PART)         // final fj
#define WS_QC  (14*PART)
#define WS_FLAG (WS_QC + NROWS)  // int[1536]

// out layout (float indices)
#define OUT_PC    0
#define OUT_TC    4608
#define OUT_NET   9216
#define OUT_POT   10752
#define OUT_MASK  12288
#define OUT_EN    602112

// =========== Kernel 1: uniform split-K=4 GEMM, double-buffered ===========
// grid (48, 6, 4). BM=32, BN=64, BK=32, 256 threads, acc 2x4.
__global__ __launch_bounds__(256) void k_gemm(const float* __restrict__ X,
                                              const float* __restrict__ W1,
                                              const float* __restrict__ sW1,
                                              float* __restrict__ ws,
                                              float* __restrict__ out) {
    __shared__ float As[2 * 32 * 34];
    __shared__ float Bs[2 * 32 * 64];
    const int t = threadIdx.x;
    if (blockIdx.x == 0 && blockIdx.y == 0 && blockIdx.z == 0 && t < 4)
        out[OUT_EN + t] = 0.0f;    // energy zero (k2 atomicAdds later)

    const int m0 = blockIdx.x * 32;
    const int gy = blockIdx.y, kz = blockIdx.z;
    const int mat = gy >> 1, half = gy & 1, n0 = half * 64;
    const float* W = (mat == 0) ? W1 : (mat == 1 ? sW1 : sW1 + 640 * 128);
    float* O = ws + (mat == 0 ? WS_H1P : (mat == 1 ? WS_FIP : WS_FJP)) + kz * PART;

    const int a_r = t >> 3, a_c = (t & 7) * 4;
    const int b_r = t >> 4, b_c = (t & 15) * 4;
    const int tx = (t & 15) * 4, ty = (t >> 4) * 2;
    const int k0 = kz * 160;

    float acc[2][4] = {};

    float4 av  = *(const float4*)&X[(m0 + a_r) * FDIM + k0 + a_c];
    float4 bv0 = *(const float4*)&W[(k0 + b_r) * HDIM + n0 + b_c];
    float4 bv1 = *(const float4*)&W[(k0 + b_r + 16) * HDIM + n0 + b_c];
    As[(a_c + 0) * 34 + a_r] = av.x;
    As[(a_c + 1) * 34 + a_r] = av.y;
    As[(a_c + 2) * 34 + a_r] = av.z;
    As[(a_c + 3) * 34 + a_r] = av.w;
    *(float4*)&Bs[b_r * 64 + b_c]        = bv0;
    *(float4*)&Bs[(b_r + 16) * 64 + b_c] = bv1;
    __syncthreads();

    for (int it = 0; it < 5; it++) {
        const int buf = it & 1;
        if (it < 4) {
            const int kk = k0 + (it + 1) * 32;
            av  = *(const float4*)&X[(m0 + a_r) * FDIM + kk + a_c];
            bv0 = *(const float4*)&W[(kk + b_r) * HDIM + n0 + b_c];
            bv1 = *(const float4*)&W[(kk + b_r + 16) * HDIM + n0 + b_c];
        }
        const float* Ab = As + buf * 1088;
        const float* Bb = Bs + buf * 2048;
#pragma unroll
        for (int k = 0; k < 32; k++) {
            float2 a = *(const float2*)&Ab[k * 34 + ty];
            float4 b = *(const float4*)&Bb[k * 64 + tx];
            acc[0][0] = fmaf(a.x, b.x, acc[0][0]);
            acc[0][1] = fmaf(a.x, b.y, acc[0][1]);
            acc[0][2] = fmaf(a.x, b.z, acc[0][2]);
            acc[0][3] = fmaf(a.x, b.w, acc[0][3]);
            acc[1][0] = fmaf(a.y, b.x, acc[1][0]);
            acc[1][1] = fmaf(a.y, b.y, acc[1][1]);
            acc[1][2] = fmaf(a.y, b.z, acc[1][2]);
            acc[1][3] = fmaf(a.y, b.w, acc[1][3]);
        }
        if (it < 4) {
            float* Aw = As + (buf ^ 1) * 1088;
            float* Bw = Bs + (buf ^ 1) * 2048;
            Aw[(a_c + 0) * 34 + a_r] = av.x;
            Aw[(a_c + 1) * 34 + a_r] = av.y;
            Aw[(a_c + 2) * 34 + a_r] = av.z;
            Aw[(a_c + 3) * 34 + a_r] = av.w;
            *(float4*)&Bw[b_r * 64 + b_c]        = bv0;
            *(float4*)&Bw[(b_r + 16) * 64 + b_c] = bv1;
            __syncthreads();
        }
    }
#pragma unroll
    for (int r = 0; r < 2; r++) {
        float4 v = make_float4(acc[r][0], acc[r][1], acc[r][2], acc[r][3]);
        *(float4*)&O[(m0 + ty + r) * HDIM + n0 + tx] = v;
    }
}

// =========== Kernel 2: partial reduce + row epilogue ===========
__global__ __launch_bounds__(256) void k_row(float* __restrict__ ws,
                                             const float* __restrict__ b1,
                                             const float* __restrict__ gam,
                                             const float* __restrict__ bet,
                                             const float* __restrict__ rmean,
                                             const float* __restrict__ rvar,
                                             const float* __restrict__ W2,
                                             const float* __restrict__ b2,
                                             const float* __restrict__ W3,
                                             const float* __restrict__ b3,
                                             const int* __restrict__ seq,
                                             float* __restrict__ out) {
    const int t = threadIdx.x, w = t >> 6, lane = t & 63;
    const int row = blockIdx.x * 4 + w;
    const long base = (long)row * 128;
    const float* h1p = ws + WS_H1P;
    const float* fip = ws + WS_FIP;
    const float* fjp = ws + WS_FJP;

    {
        float fi0 = fip[base + lane] + fip[PART + base + lane]
                  + fip[2 * PART + base + lane] + fip[3 * PART + base + lane];
        float fi1 = fip[base + 64 + lane] + fip[PART + base + 64 + lane]
                  + fip[2 * PART + base + 64 + lane] + fip[3 * PART + base + 64 + lane];
        float fj0 = fjp[base + lane] + fjp[PART + base + lane]
                  + fjp[2 * PART + base + lane] + fjp[3 * PART + base + lane];
        float fj1 = fjp[base + 64 + lane] + fjp[PART + base + 64 + lane]
                  + fjp[2 * PART + base + 64 + lane] + fjp[3 * PART + base + 64 + lane];
        ws[WS_FI + base + lane]      = fi0;
        ws[WS_FI + base + 64 + lane] = fi1;
        ws[WS_FJ + base + lane]      = fj0;
        ws[WS_FJ + base + 64 + lane] = fj1;
    }

    float h0 = h1p[base + lane] + h1p[PART + base + lane]
             + h1p[2 * PART + base + lane] + h1p[3 * PART + base + lane];
    float h1 = h1p[base + 64 + lane] + h1p[PART + base + 64 + lane]
             + h1p[2 * PART + base + 64 + lane] + h1p[3 * PART + base + 64 + lane];
    h0 = fmaxf(h0 + b1[lane], 0.0f);
    h1 = fmaxf(h1 + b1[64 + lane], 0.0f);
    h0 = gam[lane]      * (h0 - rmean[lane])      / sqrtf(rvar[lane] + 1e-5f)      + bet[lane];
    h1 = gam[64 + lane] * (h1 - rmean[64 + lane]) / sqrtf(rvar[64 + lane] + 1e-5f) + bet[64 + lane];

    float acc = b2[lane];
#pragma unroll
    for (int cc = 0; cc < 64; cc++) {
        float wv0 = W2[cc * 64 + lane];
        float wv1 = W2[(cc + 64) * 64 + lane];
        float hv0 = __uint_as_float(__builtin_amdgcn_readlane(__float_as_uint(h0), cc));
        float hv1 = __uint_as_float(__builtin_amdgcn_readlane(__float_as_uint(h1), cc));
        acc = fmaf(hv0, wv0, acc);
        acc = fmaf(hv1, wv1, acc);
    }
    float h2 = fmaxf(acc, 0.0f);
    float x0 = h2 * W3[lane * 3 + 0];
    float x1 = h2 * W3[lane * 3 + 1];
    float x2 = h2 * W3[lane * 3 + 2];
#pragma unroll
    for (int o = 32; o > 0; o >>= 1) {
        x0 += __shfl_xor(x0, o, 64);
        x1 += __shfl_xor(x1, o, 64);
        x2 += __shfl_xor(x2, o, 64);
    }
    if (lane == 0) {
        float l0 = x0 + b3[0], l1 = x1 + b3[1], l2 = x2 + b3[2];
        float m = fmaxf(l0, fmaxf(l1, l2));
        float e0 = expf(l0 - m), e1 = expf(l1 - m), e2 = expf(l2 - m);
        float s = e0 + e1 + e2;
        float pc0 = e0 / s, pc1 = e1 / s, pc2 = e2 / s;
        out[OUT_PC + row * 3 + 0] = pc0;
        out[OUT_PC + row * 3 + 1] = pc1;
        out[OUT_PC + row * 3 + 2] = pc2;
        float net = pc0 - pc1;
        out[OUT_NET + row] = net;
        ws[WS_QC + row] = net;
        ((int*)(ws + WS_FLAG))[row] = (pc0 > pc2 ? 1 : 0) | (pc1 > pc2 ? 2 : 0);
        int sid = seq[row];
        float c0 = (sid == 6 || sid == 8 || sid == 14) ? 1.0f : 0.0f;
        float c1 = (sid == 2 || sid == 3) ? 1.0f : 0.0f;
        out[OUT_TC + row * 3 + 0] = c0;
        out[OUT_TC + row * 3 + 1] = c1;
        out[OUT_TC + row * 3 + 2] = (c0 == 0.0f && c1 == 0.0f) ? 1.0f : 0.0f;
    }
}

// =========== Kernel 3: conv + pair sweep (4 rows/block, fence-free) ===========
__device__ __forceinline__ float mlp_eval(const float* __restrict__ fi, const float* __restrict__ fj,
                                          int gi, int gj, float D,
                                          float dv0, float dv1, float sb0, float sb1v,
                                          float b2v, float w3l, const float* __restrict__ sW2, int lane) {
    float h0 = fmaxf(fi[(long)gi * 128 + lane]      + fj[(long)gj * 128 + lane]      + D * dv0 + sb0,  0.0f);
    float h1 = fmaxf(fi[(long)gi * 128 + 64 + lane] + fj[(long)gj * 128 + 64 + lane] + D * dv1 + sb1v, 0.0f);
    float a0 = 0.0f, a1 = 0.0f;
#pragma unroll 8
    for (int cc = 0; cc < 64; cc++) {
        float hv0 = __uint_as_float(__builtin_amdgcn_readlane(__float_as_uint(h0), cc));
        float hv1 = __uint_as_float(__builtin_amdgcn_readlane(__float_as_uint(h1), cc));
        a0 = fmaf(hv0, sW2[cc * 64 + lane], a0);
        a1 = fmaf(hv1, sW2[(cc + 64) * 64 + lane], a1);
    }
    float x = fmaxf(a0 + a1 + b2v, 0.0f) * w3l;
#pragma unroll
    for (int o = 32; o > 0; o >>= 1) x += __shfl_xor(x, o, 64);
    return x;
}

// grid 388: blocks 0..3 conv (one per batch); blocks 4..387 -> 4 mask rows each.
__global__ __launch_bounds__(256) void k2(const float* __restrict__ S,
                                          const float* __restrict__ ws,
                                          const float* __restrict__ sW1,
                                          const float* __restrict__ sb1,
                                          const float* __restrict__ sW2,
                                          const float* __restrict__ sb2,
                                          const float* __restrict__ sW3,
                                          const float* __restrict__ sb3,
                                          const float* __restrict__ c1w, const float* __restrict__ c1b,
                                          const float* __restrict__ c2w, const float* __restrict__ c2b,
                                          const float* __restrict__ c3w, const float* __restrict__ c3b,
                                          float* __restrict__ out) {
    __shared__ char smem[6592];
    const int t = threadIdx.x;
    const int bi = blockIdx.x;

    if (bi < 4) {
        // conv via per-position register recompute; LDS = padded p0 only.
        float* p0h = (float*)smem;   // 392 floats: positions -4..387, zero-padded
        const int b = bi;
        for (int idx = t; idx < 392; idx += 256)
            p0h[idx] = (idx >= 4 && idx < 388) ? out[OUT_NET + b * LSEQ + (idx - 4)] : 0.0f;
        __syncthreads();
        for (int pos = t; pos < LSEQ; pos += 256) {
            float p2v[8][3];
#pragma unroll
            for (int o2 = 0; o2 < 8; o2++) {
                float cb = c2b[o2];
#pragma unroll
                for (int d1 = 0; d1 < 3; d1++) p2v[o2][d1] = cb;
            }
            for (int i = 0; i < 16; i++) {
                float p1v[5];
#pragma unroll
                for (int d2 = 0; d2 < 5; d2++) {
                    int q2 = pos - 2 + d2;
                    float a = c1b[i];
#pragma unroll
                    for (int k = 0; k < 5; k++)
                        a = fmaf(p0h[q2 + 2 + k], c1w[i * 5 + k], a);
                    p1v[d2] = (q2 >= 0 && q2 < LSEQ) ? fmaxf(a, 0.0f) : 0.0f;
                }
#pragma unroll
                for (int o2 = 0; o2 < 8; o2++) {
#pragma unroll
                    for (int d1 = 0; d1 < 3; d1++) {
#pragma unroll
                        for (int k = 0; k < 3; k++)
                            p2v[o2][d1] = fmaf(p1v[d1 + k], c2w[(o2 * 16 + i) * 3 + k], p2v[o2][d1]);
                    }
                }
            }
            float acc3 = c3b[0];
#pragma unroll
            for (int o2 = 0; o2 < 8; o2++) {
#pragma unroll
                for (int k = 0; k < 3; k++) {
                    int q1 = pos - 1 + k;
                    float pv = (q1 >= 0 && q1 < LSEQ) ? fmaxf(p2v[o2][k], 0.0f) : 0.0f;
                    acc3 = fmaf(pv, c3w[o2 * 3 + k], acc3);
                }
            }
            out[OUT_POT + b * LSEQ + pos] = acc3;
        }
        return;
    }

    float* sx = (float*)smem;                          // 384 f
    float* sy = sx + 384;
    float* sz = sy + 384;
    float* sq = sz + 384;
    unsigned char* sf = (unsigned char*)(sq + 384);    // 384 B
    float* red = (float*)(smem + 6544);                // 4 f -- wait, keep inside 6592
    // note: 4*384*4 + 384 = 6528; red at 6528..6543

    red = (float*)(smem + 6528);

    const float* qc = ws + WS_QC;
    const int* flags = (const int*)(ws + WS_FLAG);
    const float* fi = ws + WS_FI;
    const float* fj = ws + WS_FJ;

    const int pb = bi - 4;                 // 0..383
    const int b = pb / 96;                 // batch
    const int i0 = (pb % 96) * 4;          // first row in batch

    for (int j = t; j < LSEQ; j += 256) {
        int g = b * LSEQ + j;
        sx[j] = S[g * 3 + 0];
        sy[j] = S[g * 3 + 1];
        sz[j] = S[g * 3 + 2];
        sq[j] = qc[g];
        sf[j] = (unsigned char)flags[g];
    }
    __syncthreads();

    const int w = t >> 6, lane = t & 63;
    const int i = i0 + w;                  // this wave's row (local)
    const int row = b * LSEQ + i;          // global row
    const float six = sx[i], siy = sy[i], siz = sz[i], qi = sq[i];
    const int fli = sf[i];
    const bool posi = (fli & 1) != 0, negi = (fli & 2) != 0;
    float* mrow = out + OUT_MASK + (long)row * LSEQ;

    // per-wave MLP constants
    const float* dvec = sW1 + 1280 * 128;
    const float dv0 = dvec[lane], dv1 = dvec[lane + 64];
    const float sb0 = sb1[lane], sb1v = sb1[lane + 64];
    const float w3l = sW3[lane];
    const float b2v = sb2[lane];
    const float b3v = sb3[0];

    float esum = 0.0f;
    for (int j0 = 0; j0 < LSEQ; j0 += 64) {
        const int j = j0 + lane;
        float dx = __fsub_rn(six, sx[j]);
        float dy = __fsub_rn(siy, sy[j]);
        float dz = __fsub_rn(siz, sz[j]);
        float d2 = __fadd_rn(__fadd_rn(__fmul_rn(dx, dx), __fmul_rn(dy, dy)), __fmul_rn(dz, dz));
        d2 = __fadd_rn(d2, 1e-12f);
        float D = __fsqrt_rn(d2);
        if (j > i && D < 15.0f && D > 0.0f) {
            float num = __fmul_rn(__fmul_rn(332.0f, qi), sq[j]);
            float den = __fmul_rn(__fmul_rn(20.0f, D), D);
            esum += __fdiv_rn(num, den);
        }
        int flj = sf[j];
        bool near = (D < 4.0f);
        bool need1 = near && posi && ((flj & 2) != 0);   // q[i][j]
        bool need2 = near && negi && ((flj & 1) != 0);   // q[j][i]
        int pk = (need1 ? 1 : 0) | (need2 ? 2 : 0);
        unsigned long long mb = __ballot(pk != 0);
        unsigned long long hitbits = 0ull;
        while (mb) {
            int jl = __ffsll((long long)mb) - 1;
            mb &= mb - 1ull;
            int pf = __shfl(pk, jl, 64);
            float Dj = __shfl(D, jl, 64);
            int gj = b * LSEQ + j0 + jl;
            bool hit = false;
            if (pf & 1) {
                float x = mlp_eval(fi, fj, row, gj, Dj, dv0, dv1, sb0, sb1v, b2v, w3l, sW2, lane);
                hit = (x + b3v) > 0.0f;
            }
            if (!hit && (pf & 2)) {
                float x = mlp_eval(fi, fj, gj, row, Dj, dv0, dv1, sb0, sb1v, b2v, w3l, sW2, lane);
                hit = (x + b3v) > 0.0f;
            }
            if (hit) hitbits |= (1ull << jl);
        }
        mrow[j] = ((hitbits >> lane) & 1ull) ? 1.0f : 0.0f;
    }
#pragma unroll
    for (int o = 32; o > 0; o >>= 1) esum += __shfl_xor(esum, o, 64);
    if (lane == 0) red[w] = esum;
    __syncthreads();
    if (t == 0) {
        float s = red[0] + red[1] + red[2] + red[3];
        atomicAdd(&out[OUT_EN + b], s);   // 96 blocks/address, 4 addresses
    }
}

extern "C" void kernel_launch(void* const* d_in, const int* in_sizes, int n_in,
                              void* d_out, int out_size, void* d_ws, size_t ws_size,
                              hipStream_t stream) {
    const float* X     = (const float*)d_in[0];
    const int*   seq   = (const int*)d_in[1];
    const float* S     = (const float*)d_in[2];
    const float* W1    = (const float*)d_in[3];
    const float* b1    = (const float*)d_in[4];
    const float* gam   = (const float*)d_in[5];
    const float* bet   = (const float*)d_in[6];
    const float* rmean = (const float*)d_in[7];
    const float* rvar  = (const float*)d_in[8];
    const float* W2    = (const float*)d_in[9];
    const float* b2    = (const float*)d_in[10];
    const float* W3    = (const float*)d_in[11];
    const float* b3    = (const float*)d_in[12];
    const float* sW1   = (const float*)d_in[13];
    const float* sb1   = (const float*)d_in[14];
    const float* sW2   = (const float*)d_in[15];
    const float* sb2   = (const float*)d_in[16];
    const float* sW3   = (const float*)d_in[17];
    const float* sb3   = (const float*)d_in[18];
    const float* c1w   = (const float*)d_in[19];
    const float* c1b   = (const float*)d_in[20];
    const float* c2w   = (const float*)d_in[21];
    const float* c2b   = (const float*)d_in[22];
    const float* c3w   = (const float*)d_in[23];
    const float* c3b   = (const float*)d_in[24];

    float* out = (float*)d_out;
    float* ws  = (float*)d_ws;

    hipLaunchKernelGGL(k_gemm, dim3(48, 6, 4), dim3(256), 0, stream, X, W1, sW1, ws, out);
    hipLaunchKernelGGL(k_row, dim3(384), dim3(256), 0, stream,
                       ws, b1, gam, bet, rmean, rvar, W2, b2, W3, b3, seq, out);
    hipLaunchKernelGGL(k2, dim3(388), dim3(256), 0, stream,
                       S, ws, sW1, sb1, sW2, sb2, sW3, sb3,
                       c1w, c1b, c2w, c2b, c3w, c3b, out);
}